// Round 11
// baseline (393.930 us; speedup 1.0000x reference)
//
#include <hip/hip_runtime.h>
#include <hip/hip_bf16.h>
#include <cstdint>
#include <cstddef>

// MultiheadAttention: B=4, NQ=NK=2048, D=1024, H=16, HD=64.
// Pipeline (fast path, ws>=72MiB): cvt_all (fp32->bf16 for q,k,v,Wq..Wo),
// fused Q/K/V projections via all-bf16 gemm_fast (m97 geometry: BK=64,
// single-buffered, 32 MFMA/wave/iter), flash attention (32 q/wave), O-proj.
// Score scale 1/8*log2(e) folded into Q-proj epilogue (flash uses raw exp2).
//
// R10 post-mortem: both changes landed (flash 104->91 w/ 4 blocks/CU; gemm
// out of top-5 w/ coalesced Vt). flash VALUBusy 39% > MfmaUtil 31% -> the
// softmax VALU chain (32 exp2 + 32 cvt + 32 lp-adds) is the hot pipe.
// R11: (a) flash: l-sum via ones-MFMA (4 MFMA/iter on the 31%-busy matrix
// pipe replace 32 VALU adds/iter; C-layout puts lacc[r] on the exact lane
// that writes O-row q4*4+r -> the shfl reduce is deleted too), plus
// s_setprio(1) around both MFMA clusters (+4-7% measured on attn, m191).
// (b) gemm_fast: __launch_bounds__(256,4) -> 4 blocks/CU (same TLP
// mechanism that took flash 132->91; VGPR ~90 fits the 128 budget).

typedef __bf16 bf16x8 __attribute__((ext_vector_type(8)));
typedef float f32x4 __attribute__((ext_vector_type(4)));

#define BB 4
#define NQ 2048
#define NK 2048
#define DD 1024
#define HH 16
#define HD 64

#define QSCALE (0.125f * 1.4426950408889634f)  // 1/sqrt(HD) * log2(e)

#if __has_builtin(__builtin_amdgcn_exp2f)
#define EXP2F(x) __builtin_amdgcn_exp2f(x)
#else
#define EXP2F(x) exp2f(x)
#endif

__device__ inline void gld_lds16(const void* g, void* lds) {
  __builtin_amdgcn_global_load_lds(
      (__attribute__((address_space(1))) unsigned int*)(g),
      (__attribute__((address_space(3))) unsigned int*)(lds),
      16, 0, 0);
}

// fp32-vs-bf16 probe (FETCH_SIZE evidence: inputs are fp32; probe keeps the
// kernel correct either way).
__device__ inline bool probe_f32(const void* p) {
  const unsigned short* u = (const unsigned short*)p;
  int bad = 0;
#pragma unroll
  for (int i = 0; i < 64; ++i) {
    const int e = (u[2 * i] >> 7) & 0xFF;
    bad += (e > 0x8F) ? 1 : 0;
  }
  return bad >= 4;
}

__device__ inline bf16x8 cvt8(const float* src) {
  union { bf16x8 v; __hip_bfloat16 h[8]; } u;
#pragma unroll
  for (int j = 0; j < 8; ++j) u.h[j] = __float2bfloat16(src[j]);
  return u.v;
}

// ---------------------------------------------------------------------------
// cvt_all: fp32 -> bf16 (or bf16 copy) for q,k,v (512 blocks each) and the
// four W matrices (64 blocks each). 2048 vec8 per block, fully coalesced.
__global__ __launch_bounds__(256) void cvt_all(
    const void* __restrict__ q, const void* __restrict__ k,
    const void* __restrict__ v,
    const void* __restrict__ Wq, const void* __restrict__ Wk,
    const void* __restrict__ Wv, const void* __restrict__ Wo,
    __hip_bfloat16* __restrict__ qb, __hip_bfloat16* __restrict__ kb,
    __hip_bfloat16* __restrict__ vb, __hip_bfloat16* __restrict__ Wb) {
  const int bidx = blockIdx.x;
  const void* src; __hip_bfloat16* dst; size_t voff;
  if (bidx < 1536) {
    const int s = bidx >> 9;
    src = s == 0 ? q : (s == 1 ? k : v);
    dst = s == 0 ? qb : (s == 1 ? kb : vb);
    voff = (size_t)(bidx & 511) * 2048;
  } else {
    const int wi = (bidx - 1536) >> 6;
    src = wi == 0 ? Wq : (wi == 1 ? Wk : (wi == 2 ? Wv : Wo));
    dst = Wb + (size_t)wi * (DD * DD);
    voff = (size_t)((bidx - 1536) & 63) * 2048;
  }
  __shared__ int sflag;
  if (threadIdx.x == 0) sflag = probe_f32(src) ? 1 : 0;
  __syncthreads();
  const bool f32 = sflag != 0;
  const int t = threadIdx.x;
#pragma unroll
  for (int i = 0; i < 8; ++i) {
    const size_t j = voff + (size_t)i * 256 + t;
    if (f32) {
      union { f32x4 v2[2]; float f[8]; } u;
      const f32x4* s4 = (const f32x4*)src;
      u.v2[0] = s4[j * 2]; u.v2[1] = s4[j * 2 + 1];
      *(bf16x8*)(dst + j * 8) = cvt8(u.f);
    } else {
      *(f32x4*)(dst + j * 8) = ((const f32x4*)src)[j];
    }
  }
}

// ---------------------------------------------------------------------------
// gemm_fast: all-bf16 C[8192,1024] = A * W^T, epilogue (acc+bias)*scale.
// cfg = cfg0 + z: 0=Q(scale QSCALE) 1=K 2=V(Vt permute) 3=O(dtype-follow).
// m97-exact: BK=64, 128x128 tile, single-buffered 32KB LDS, 2 barriers/iter,
// 32 MFMA + 8 gld_lds16 + 16 ds_read_b128 per wave-iter. R11: (256,4) ->
// 4 blocks/CU cross-block TLP to hide the barrier drain.
// mode-1 epilogue: LDS-transpose (sT[col][row^swz] per wc-half in sA/sB),
// then coalesced 16B row writes into Vt.
// 1-D grid; decode: xcd=bid&7, idx=bid>>3, z=idx>>6, r=idx&63,
// bm=xcd*8+(r>>3), bn=r&7  (bn-fast within a bm stripe, per-XCD).
__global__ __launch_bounds__(256, 4) void gemm_fast(
    const __hip_bfloat16* __restrict__ qb, const __hip_bfloat16* __restrict__ kb,
    const __hip_bfloat16* __restrict__ vb, const __hip_bfloat16* __restrict__ At,
    const __hip_bfloat16* __restrict__ Wb,
    const void* __restrict__ bq, const void* __restrict__ bk,
    const void* __restrict__ bv, const void* __restrict__ bo,
    const void* __restrict__ WoOrig,
    void* __restrict__ Qp, void* __restrict__ Kp,
    void* __restrict__ Vt, void* __restrict__ Out, int cfg0) {
  __shared__ __align__(16) __hip_bfloat16 sA[128 * 64];
  __shared__ __align__(16) __hip_bfloat16 sB[128 * 64];
  const int t = threadIdx.x;
  const int wave = t >> 6, lane = t & 63;
  const int q4 = lane >> 4, c16 = lane & 15;
  const int xr = c16 & 7;
  const int wr = wave >> 1, wc = wave & 1;

  const int bid = blockIdx.x;
  const int xcd = bid & 7, idx = bid >> 3;
  const int z = idx >> 6;
  const int r6 = idx & 63;
  const int bm = xcd * 8 + (r6 >> 3);
  const int bn = r6 & 7;
  const int cfg = cfg0 + z;

  const __hip_bfloat16* A; const void* biasv; void* Cv; int mode; float scale = 1.f;
  if (cfg == 0)      { A = qb; biasv = bq; Cv = Qp; mode = 0; scale = QSCALE; }
  else if (cfg == 1) { A = kb; biasv = bk; Cv = Kp; mode = 0; }
  else if (cfg == 2) { A = vb; biasv = bv; Cv = Vt; mode = 1; }
  else               { A = At; biasv = bo; Cv = Out; mode = 2; }
  const __hip_bfloat16* Bm = Wb + (size_t)cfg * (DD * DD);

  const bool bias_f32 = probe_f32(biasv);
  const bool c_f32 = (mode == 2) && probe_f32(WoOrig);

  f32x4 acc[4][4];
#pragma unroll
  for (int i = 0; i < 4; ++i)
#pragma unroll
    for (int j = 0; j < 4; ++j) acc[i][j] = (f32x4){0.f, 0.f, 0.f, 0.f};

  const size_t baseA = (size_t)bm * 128 * DD;
  const size_t baseB = (size_t)bn * 128 * DD;

  // per-thread staging offsets (elements); slot=i*256+t (1024 slots of 16B),
  // row=slot>>3, pg=(slot&7)^(row&7) (source-side 8-piece swizzle)
  size_t offA[4], offB[4];
  int lslot[4];
#pragma unroll
  for (int i = 0; i < 4; ++i) {
    const int slot = i * 256 + t;
    const int row = slot >> 3, pg = (slot & 7) ^ (row & 7);
    lslot[i] = slot;
    offA[i] = baseA + (size_t)row * DD + pg * 8;
    offB[i] = baseB + (size_t)row * DD + pg * 8;
  }

  for (int k0 = 0; k0 < DD; k0 += 64) {
    __syncthreads();   // previous iteration's ds_reads complete
#pragma unroll
    for (int i = 0; i < 4; ++i)
      gld_lds16(A + offA[i] + k0, sA + lslot[i] * 8);
#pragma unroll
    for (int i = 0; i < 4; ++i)
      gld_lds16(Bm + offB[i] + k0, sB + lslot[i] * 8);
    __syncthreads();   // vmcnt(0) drain: tile staged

#pragma unroll
    for (int ks = 0; ks < 2; ++ks) {
      bf16x8 af[4], bfm[4];
#pragma unroll
      for (int rt = 0; rt < 4; ++rt)
        af[rt] = *(const bf16x8*)(sA + (wr * 64 + rt * 16 + c16) * 64 +
                                  ((ks * 4 + q4) ^ xr) * 8);
#pragma unroll
      for (int ct = 0; ct < 4; ++ct)
        bfm[ct] = *(const bf16x8*)(sB + (wc * 64 + ct * 16 + c16) * 64 +
                                   ((ks * 4 + q4) ^ xr) * 8);
#pragma unroll
      for (int rt = 0; rt < 4; ++rt)
#pragma unroll
        for (int ct = 0; ct < 4; ++ct)
          acc[rt][ct] = __builtin_amdgcn_mfma_f32_16x16x32_bf16(af[rt], bfm[ct],
                                                                acc[rt][ct], 0, 0, 0);
    }
  }

  if (mode == 1) {
    // Coalesced Vt epilogue: transpose via LDS. Wave-half wc -> sA (wc=0) /
    // sB (wc=1), layout sT[col(0..63)][row(0..127) ^ ((col&7)<<3)].
    __syncthreads();   // all MFMA reads of sA/sB done before overwrite
    __hip_bfloat16* sT = wc ? sB : sA;
#pragma unroll
    for (int ct = 0; ct < 4; ++ct) {
      const int col = ct * 16 + c16;                 // 0..63 within half
      const int colg = bn * 128 + wc * 64 + col;     // global n
      const float bvx = bias_f32 ? ((const float*)biasv)[colg]
                                 : __bfloat162float(((const __hip_bfloat16*)biasv)[colg]);
      const int sw = (col & 7) << 3;
#pragma unroll
      for (int rt = 0; rt < 4; ++rt) {
        union { uint2 u; __hip_bfloat16 hx[4]; } pk;
#pragma unroll
        for (int r = 0; r < 4; ++r)
          pk.hx[r] = __float2bfloat16((acc[rt][ct][r] + bvx) * scale);
        const int rowl = wr * 64 + rt * 16 + q4 * 4;
        *(uint2*)(sT + col * 128 + (rowl ^ sw)) = pk.u;
      }
    }
    __syncthreads();   // transpose staged (rows come from both wr waves)
    const int bb = bm >> 4;            // batch  (row>>11)
    const int kb0 = (bm & 15) * 128;   // key base (row&2047)
#pragma unroll
    for (int i = 0; i < 8; ++i) {
      const int idx2 = i * 256 + t;    // 0..2047 = 2 halves x 64 cols x 16 kc
      const int half = idx2 >> 10;
      const int rem = idx2 & 1023;
      const int col = rem >> 4;        // hd 0..63
      const int kc = rem & 15;         // 8-key chunk
      const __hip_bfloat16* sTh = half ? sB : sA;
      bf16x8 vv = *(const bf16x8*)(sTh + col * 128 + ((kc * 8) ^ ((col & 7) << 3)));
      const int hh = bn * 2 + half;
      *(bf16x8*)((__hip_bfloat16*)Cv +
                 (size_t)((bb * HH + hh) * HD + col) * NK + kb0 + kc * 8) = vv;
    }
    return;
  }

  // epilogue (modes 0,2): C/D layout row=(lane>>4)*4+reg, col=lane&15
  const int row0 = bm * 128 + wr * 64 + q4 * 4;
  const int col0 = bn * 128 + wc * 64 + c16;
#pragma unroll
  for (int ct = 0; ct < 4; ++ct) {
    const int col = col0 + ct * 16;
    const float bvx = bias_f32 ? ((const float*)biasv)[col]
                               : __bfloat162float(((const __hip_bfloat16*)biasv)[col]);
#pragma unroll
    for (int rt = 0; rt < 4; ++rt) {
#pragma unroll
      for (int r = 0; r < 4; ++r) {
        const int row = row0 + rt * 16 + r;
        const float val = (acc[rt][ct][r] + bvx) * scale;
        if (c_f32) {
          ((float*)Cv)[(size_t)row * DD + col] = val;
        } else {
          ((__hip_bfloat16*)Cv)[(size_t)row * DD + col] = __float2bfloat16(val);
        }
      }
    }
  }
}

// ---------------------------------------------------------------------------
// Fallback path (R3): reg-staged cvt gemm, used when ws is too small.
__device__ inline void ld_slot(bool f32, const void* basep, size_t eoff,
                               f32x4& lo, f32x4& hi) {
  if (f32) {
    const f32x4* p = (const f32x4*)((const float*)basep + eoff);
    lo = p[0]; hi = p[1];
  } else {
    lo = *(const f32x4*)((const __hip_bfloat16*)basep + eoff);
  }
}

__device__ inline void st_slot(bool f32, __hip_bfloat16* dst, f32x4 lo, f32x4 hi) {
  if (f32) {
    union { f32x4 v[2]; float f[8]; } u;
    u.v[0] = lo; u.v[1] = hi;
    *(bf16x8*)dst = cvt8(u.f);
  } else {
    *(f32x4*)dst = lo;
  }
}

__global__ __launch_bounds__(256, 3) void gemm_mha(
    const void* __restrict__ qin, const void* __restrict__ kin,
    const void* __restrict__ vin, const void* __restrict__ ain,
    const void* __restrict__ Wq, const void* __restrict__ bq,
    const void* __restrict__ Wk, const void* __restrict__ bk,
    const void* __restrict__ Wv, const void* __restrict__ bv,
    const void* __restrict__ Wo, const void* __restrict__ bo,
    void* __restrict__ Qp, void* __restrict__ Kp,
    void* __restrict__ Vt, void* __restrict__ Out, int cfg0) {
  __shared__ __align__(16) __hip_bfloat16 sA[2][128 * 32];
  __shared__ __align__(16) __hip_bfloat16 sB[2][128 * 32];
  const int t = threadIdx.x;
  const int wave = t >> 6, lane = t & 63;
  const int q4 = lane >> 4, c16 = lane & 15;
  const int wr = wave >> 1, wc = wave & 1;

  const int bid = blockIdx.x;
  const int xcd = bid & 7, idx = bid >> 3;
  const int z = idx >> 6;
  const int r6 = idx & 63;
  const int bm = xcd * 8 + (r6 >> 3);
  const int bn = r6 & 7;
  const int cfg = cfg0 + z;

  const void *Av, *Bv, *biasv; void* Cv; int mode; float scale = 1.f;
  if (cfg == 0)      { Av = qin; Bv = Wq; biasv = bq; Cv = Qp; mode = 0; scale = QSCALE; }
  else if (cfg == 1) { Av = kin; Bv = Wk; biasv = bk; Cv = Kp; mode = 0; }
  else if (cfg == 2) { Av = vin; Bv = Wv; biasv = bv; Cv = Vt; mode = 1; }
  else               { Av = ain; Bv = Wo; biasv = bo; Cv = Out; mode = 2; }

  const bool a_f32 = probe_f32(Av);
  const bool b_f32 = probe_f32(Bv);
  const bool c_f32 = (mode == 2) && b_f32;

  f32x4 acc[4][4];
#pragma unroll
  for (int i = 0; i < 4; ++i)
#pragma unroll
    for (int j = 0; j < 4; ++j) acc[i][j] = (f32x4){0.f, 0.f, 0.f, 0.f};

  const size_t baseA = (size_t)bm * 128 * DD;
  const size_t baseB = (size_t)bn * 128 * DD;
  const int po = ((q4) ^ (c16 & 3)) * 8;

  size_t offA[2], offB[2];
  int lslot[2];
#pragma unroll
  for (int i = 0; i < 2; ++i) {
    const int slot = i * 256 + t;
    const int row = slot >> 2, pg = (slot & 3) ^ (row & 3);
    lslot[i] = slot;
    offA[i] = baseA + (size_t)row * DD + pg * 8;
    offB[i] = baseB + (size_t)row * DD + pg * 8;
  }

  f32x4 Alo[2], Ahi[2], Blo[2], Bhi[2];
#pragma unroll
  for (int i = 0; i < 2; ++i) {
    ld_slot(a_f32, Av, offA[i], Alo[i], Ahi[i]);
    ld_slot(b_f32, Bv, offB[i], Blo[i], Bhi[i]);
  }

  for (int k0 = 0, it = 0; k0 < DD; k0 += 32, ++it) {
    const int p = it & 1;
#pragma unroll
    for (int i = 0; i < 2; ++i) {
      st_slot(a_f32, &sA[p][lslot[i] * 8], Alo[i], Ahi[i]);
      st_slot(b_f32, &sB[p][lslot[i] * 8], Blo[i], Bhi[i]);
    }
    __syncthreads();

    if (k0 + 32 < DD) {
#pragma unroll
      for (int i = 0; i < 2; ++i) {
        ld_slot(a_f32, Av, offA[i] + k0 + 32, Alo[i], Ahi[i]);
        ld_slot(b_f32, Bv, offB[i] + k0 + 32, Blo[i], Bhi[i]);
      }
    }

    bf16x8 af[4], bfm[4];
#pragma unroll
    for (int rt = 0; rt < 4; ++rt)
      af[rt] = *(const bf16x8*)(&sA[p][0] + (wr * 64 + rt * 16 + c16) * 32 + po);
#pragma unroll
    for (int ct = 0; ct < 4; ++ct)
      bfm[ct] = *(const bf16x8*)(&sB[p][0] + (wc * 64 + ct * 16 + c16) * 32 + po);
#pragma unroll
    for (int rt = 0; rt < 4; ++rt)
#pragma unroll
      for (int ct = 0; ct < 4; ++ct)
        acc[rt][ct] = __builtin_amdgcn_mfma_f32_16x16x32_bf16(af[rt], bfm[ct],
                                                              acc[rt][ct], 0, 0, 0);
  }

  const int row0 = bm * 128 + wr * 64 + q4 * 4;
  const int col0 = bn * 128 + wc * 64 + c16;
#pragma unroll
  for (int ct = 0; ct < 4; ++ct) {
    const int col = col0 + ct * 16;
    const float bvx = b_f32 ? ((const float*)biasv)[col]
                            : __bfloat162float(((const __hip_bfloat16*)biasv)[col]);
#pragma unroll
    for (int rt = 0; rt < 4; ++rt) {
#pragma unroll
      for (int r = 0; r < 4; ++r) {
        const int row = row0 + rt * 16 + r;
        const float val = (acc[rt][ct][r] + bvx) * scale;
        if (mode == 1) {
          const int b = row >> 11, key = row & 2047;
          const int h = col >> 6, hd = col & 63;
          ((__hip_bfloat16*)Cv)[(size_t)((b * HH + h) * HD + hd) * NK + key] =
              __float2bfloat16(val);
        } else if (c_f32) {
          ((float*)Cv)[(size_t)row * DD + col] = val;
        } else {
          ((__hip_bfloat16*)Cv)[(size_t)row * DD + col] = __float2bfloat16(val);
        }
      }
    }
  }
}

// ---------------------------------------------------------------------------
// Flash attention, S^T orientation. Qp pre-scaled by QSCALE (incl log2e);
// Kp: [B,N,D] bf16; Vt: [B,H,HD,NK]. One block = (b,h,128-query tile); wave
// owns 32 queries (2 groups of 16); K/bv LDS reads shared by both groups.
// V single-buffered; K double-buffered. LDS 40KB -> 4 blocks/CU.
// R11: l-sum via ones-MFMA: lacc[qg] = mfma(ap, ones, lacc) accumulates
// sum_k P[q][k] in the C-layout (lacc[r] <-> O-row q4*4+r on the same lane)
// -> removes 32 VALU adds/iter AND the end shfl reduce. s_setprio(1) wraps
// both MFMA clusters (attn-measured +4-7%, m191).
// 1-D grid (1024); decode: xcd=bid&7, idx=bid>>3, bh=xcd*8+(idx>>4),
// qt=idx&15.
__global__ __launch_bounds__(256, 4) void flash_attn(
    const __hip_bfloat16* Qp, const __hip_bfloat16* __restrict__ Kp,
    const __hip_bfloat16* __restrict__ Vt, __hip_bfloat16* Ao) {
  __shared__ __align__(16) __hip_bfloat16 sQP[128 * 64];  // Q[128][64] then P[128][64] (16 KB)
  __shared__ __align__(16) __hip_bfloat16 sK[2][64 * 64]; // 16 KB dbuf
  __shared__ __align__(16) __hip_bfloat16 sV[64 * 64];    // 8 KB single

  const int t = threadIdx.x;
  const int wave = t >> 6, lane = t & 63;
  const int q4 = lane >> 4, c16 = lane & 15;
  const int xr = c16 & 7;

  const int bid = blockIdx.x;
  const int xcd = bid & 7, idx = bid >> 3;   // idx 0..127
  const int bh = xcd * 8 + (idx >> 4);       // 0..63
  const int qt = idx & 15;                   // 0..15
  const int b = bh >> 4, h = bh & 15;

  // stage Q tile (128x64) + K tile 0, swizzled (pg=(slot&7)^(row&7))
#pragma unroll
  for (int i = 0; i < 4; ++i) {
    const int slot = i * 256 + t;
    const int row = slot >> 3, pg = (slot & 7) ^ (row & 7);
    gld_lds16(Qp + ((size_t)(b * NQ + qt * 128 + row) * DD + h * 64 + pg * 8),
              sQP + slot * 8);
  }
#pragma unroll
  for (int i = 0; i < 2; ++i) {
    const int slot = i * 256 + t;
    const int row = slot >> 3, pg = (slot & 7) ^ (row & 7);
    gld_lds16(Kp + ((size_t)(b * NK + row) * DD + h * 64 + pg * 8),
              &sK[0][0] + slot * 8);
  }

  f32x4 o[2][4];
#pragma unroll
  for (int g = 0; g < 2; ++g)
#pragma unroll
    for (int i = 0; i < 4; ++i) o[g][i] = (f32x4){0.f, 0.f, 0.f, 0.f};
  f32x4 lacc[2];
  lacc[0] = (f32x4){0.f, 0.f, 0.f, 0.f};
  lacc[1] = (f32x4){0.f, 0.f, 0.f, 0.f};

  // all-ones bf16x8 B-fragment for the l row-sum MFMA
  union { bf16x8 v; unsigned short u[8]; } one8;
#pragma unroll
  for (int j = 0; j < 8; ++j) one8.u[j] = 0x3F80;  // bf16 1.0

  __syncthreads();  // Q + K0 staged

  bf16x8 aq[2][2];
#pragma unroll
  for (int qg = 0; qg < 2; ++qg)
#pragma unroll
    for (int ks = 0; ks < 2; ++ks)
      aq[qg][ks] = *(const bf16x8*)(sQP + (wave * 32 + qg * 16 + c16) * 64 +
                                    ((ks * 4 + q4) ^ xr) * 8);
  // aq rows are wave-private (rows wave*32..+31) -> safe vs this wave's own
  // later P stores; cross-wave Q staging was fenced by the barrier above.

  const int prow0 = wave * 32 + c16;        // query group 0 row
  const int prow1 = wave * 32 + 16 + c16;   // query group 1 row

  for (int kt = 0; kt < NK / 64; ++kt) {
    const int p = kt & 1;
    // stage V[kt] into sV (prev iter's B2 guarantees PV[kt-1] reads done)
#pragma unroll
    for (int i = 0; i < 2; ++i) {
      const int slot = i * 256 + t;
      const int row = slot >> 3, pg = (slot & 7) ^ (row & 7);
      gld_lds16(Vt + ((size_t)(bh * 64 + row) * NK + kt * 64 + pg * 8),
                &sV[0] + slot * 8);
    }
    // prefetch K[kt+1] into sK[p^1]
    if (kt + 1 < NK / 64) {
#pragma unroll
      for (int i = 0; i < 2; ++i) {
        const int slot = i * 256 + t;
        const int row = slot >> 3, pg = (slot & 7) ^ (row & 7);
        gld_lds16(Kp + ((size_t)(b * NK + (kt + 1) * 64 + row) * DD + h * 64 + pg * 8),
                  &sK[p ^ 1][0] + slot * 8);
      }
    }

    // S^T tiles: keys ct*16+q4*4+r, query c16 per group (K reads shared)
    f32x4 s[2][4];
    __builtin_amdgcn_s_setprio(1);
#pragma unroll
    for (int ct = 0; ct < 4; ++ct) {
      bf16x8 bk0 = *(const bf16x8*)(&sK[p][0] + (ct * 16 + c16) * 64 + ((0 + q4) ^ xr) * 8);
      bf16x8 bk1 = *(const bf16x8*)(&sK[p][0] + (ct * 16 + c16) * 64 + ((4 + q4) ^ xr) * 8);
#pragma unroll
      for (int qg = 0; qg < 2; ++qg) {
        f32x4 z = (f32x4){0.f, 0.f, 0.f, 0.f};
        z = __builtin_amdgcn_mfma_f32_16x16x32_bf16(bk0, aq[qg][0], z, 0, 0, 0);
        z = __builtin_amdgcn_mfma_f32_16x16x32_bf16(bk1, aq[qg][1], z, 0, 0, 0);
        s[qg][ct] = z;
      }
    }
    __builtin_amdgcn_s_setprio(0);

    // p = exp2(s); pack 4 keys -> one 8B store into sP[query][key]
#pragma unroll
    for (int qg = 0; qg < 2; ++qg) {
      const int prow = qg ? prow1 : prow0;
#pragma unroll
      for (int ct = 0; ct < 4; ++ct) {
        union { uint2 u; __hip_bfloat16 hx[4]; } pk;
#pragma unroll
        for (int r = 0; r < 4; ++r)
          pk.hx[r] = __float2bfloat16(EXP2F(s[qg][ct][r]));
        const int pc = (ct * 2 + (q4 >> 1)) ^ xr;
        *(uint2*)(sQP + prow * 64 + pc * 8 + (q4 & 1) * 4) = pk.u;
      }
    }
    // P rows are wave-private: same-wave ds ordering suffices, no barrier.

    __syncthreads();  // B1: V[kt] (+K[kt+1]) drained into LDS

    // O += P V; l += P 1 (ones-MFMA; bv reads shared by both query groups)
    __builtin_amdgcn_s_setprio(1);
#pragma unroll
    for (int kk = 0; kk < 2; ++kk) {
      bf16x8 bvf[4];
#pragma unroll
      for (int ct2 = 0; ct2 < 4; ++ct2)
        bvf[ct2] = *(const bf16x8*)(&sV[0] + (ct2 * 16 + c16) * 64 + ((kk * 4 + q4) ^ xr) * 8);
      bf16x8 ap0 = *(const bf16x8*)(sQP + prow0 * 64 + ((kk * 4 + q4) ^ xr) * 8);
      bf16x8 ap1 = *(const bf16x8*)(sQP + prow1 * 64 + ((kk * 4 + q4) ^ xr) * 8);
      lacc[0] = __builtin_amdgcn_mfma_f32_16x16x32_bf16(ap0, one8.v, lacc[0], 0, 0, 0);
      lacc[1] = __builtin_amdgcn_mfma_f32_16x16x32_bf16(ap1, one8.v, lacc[1], 0, 0, 0);
#pragma unroll
      for (int ct2 = 0; ct2 < 4; ++ct2) {
        o[0][ct2] = __builtin_amdgcn_mfma_f32_16x16x32_bf16(ap0, bvf[ct2], o[0][ct2], 0, 0, 0);
        o[1][ct2] = __builtin_amdgcn_mfma_f32_16x16x32_bf16(ap1, bvf[ct2], o[1][ct2], 0, 0, 0);
      }
    }
    __builtin_amdgcn_s_setprio(0);

    __syncthreads();  // B2: PV reads done -> next iter may overwrite sV
  }

  // l is already per-lane complete: lacc[qg][r] = sum over all keys for
  // query row q4*4+r of group qg (replicated across c16) — the exact rows
  // this lane writes below. No cross-lane reduce needed.
  float linv[2][4];
#pragma unroll
  for (int qg = 0; qg < 2; ++qg)
#pragma unroll
    for (int r = 0; r < 4; ++r) linv[qg][r] = 1.f / lacc[qg][r];

  // epilogue: O C-layout row=query(q4*4+r), col=hd(ct2*16+c16)
#pragma unroll
  for (int qg = 0; qg < 2; ++qg)
#pragma unroll
    for (int ct2 = 0; ct2 < 4; ++ct2)
#pragma unroll
      for (int r = 0; r < 4; ++r) {
        const size_t row = (size_t)(b * NQ + qt * 128 + wave * 32 + qg * 16 + q4 * 4 + r);
        Ao[row * DD + h * 64 + ct2 * 16 + c16] = __float2bfloat16(o[qg][ct2][r] * linv[qg][r]);
      }
}

extern "C" void kernel_launch(void* const* d_in, const int* in_sizes, int n_in,
                              void* d_out, int out_size, void* d_ws, size_t ws_size,
                              hipStream_t stream) {
  const void* q  = d_in[0];
  const void* k  = d_in[1];
  const void* v  = d_in[2];
  const void* Wq = d_in[3];
  const void* bq = d_in[4];
  const void* Wk = d_in[5];
  const void* bk = d_in[6];
  const void* Wv = d_in[7];
  const void* bv = d_in[8];
  const void* Wo = d_in[9];
  const void* bo = d_in[10];

  const size_t MP = (size_t)BB * NQ;       // 8192
  const size_t MAT = MP * DD;              // 8.39M elems
  __hip_bfloat16* Qp = (__hip_bfloat16*)d_ws;   // also At (alias, safe)
  __hip_bfloat16* Vt = Qp + MAT;
  __hip_bfloat16* Kp = (__hip_bfloat16*)d_out;  // dead before final GEMM writes
  __hip_bfloat16* At = Qp;

  // fast path needs: Qp 16M | Vt 16M | kb 16M | vb 16M | Wb 8M = 72 MiB
  const size_t NEED = (4 * MAT + 4 * (size_t)(DD * DD)) * sizeof(__hip_bfloat16);
  if (ws_size >= NEED) {
    __hip_bfloat16* kb = Vt + MAT;
    __hip_bfloat16* vb = kb + MAT;
    __hip_bfloat16* Wb = vb + MAT;
    __hip_bfloat16* qb = (__hip_bfloat16*)d_out + MAT;  // upper half of d_out

    cvt_all<<<dim3(1792), 256, 0, stream>>>(q, k, v, Wq, Wk, Wv, Wo,
                                            qb, kb, vb, Wb);
    gemm_fast<<<dim3(1536), 256, 0, stream>>>(qb, kb, vb, At, Wb,
                                              bq, bk, bv, bo, Wo,
                                              Qp, Kp, Vt, d_out, 0);
    flash_attn<<<dim3(1024), 256, 0, stream>>>(Qp, Kp, Vt, At);
    gemm_fast<<<dim3(512), 256, 0, stream>>>(qb, kb, vb, At, Wb,
                                             bq, bk, bv, bo, Wo,
                                             Qp, Kp, Vt, d_out, 3);
  } else {
    // fallback: R3 path
    gemm_mha<<<dim3(1536), 256, 0, stream>>>(
        q, k, v, At, Wq, bq, Wk, bk, Wv, bv, Wo, bo, Qp, Kp, Vt, d_out, 0);
    flash_attn<<<dim3(1024), 256, 0, stream>>>(Qp, Kp, Vt, At);
    gemm_mha<<<dim3(512), 256, 0, stream>>>(
        q, k, v, At, Wq, bq, Wk, bk, Wv, bv, Wo, bo, Qp, Kp, Vt, d_out, 3);
  }
}

// Round 13
// 330.944 us; speedup vs baseline: 1.1903x; 1.1903x over previous
//
#include <hip/hip_runtime.h>
#include <hip/hip_bf16.h>
#include <cstdint>
#include <cstddef>

// MultiheadAttention: B=4, NQ=NK=2048, D=1024, H=16, HD=64.
// Pipeline (fast path, ws>=72MiB): cvt_all (fp32->bf16 for q,k,v,Wq..Wo),
// fused Q/K/V projections via all-bf16 gemm_fast (m97 geometry: BK=64,
// single-buffered, 32 MFMA/wave/iter), flash attention (32 q/wave), O-proj.
// Score scale 1/8*log2(e) folded into Q-proj epilogue (flash uses raw exp2).
//
// R11 post-mortem: __launch_bounds__(256,4) on gemm_fast SPILLED (VGPR 84->64,
// WRITE_SIZE 48->175 MB scratch traffic, dur 100->112) -> total 339->394.
// R12: revert gemm_fast to (256,3) (measured-good R10 config). Flash keeps
// the R11 l-sum-via-ones-MFMA + setprio so its true effect is measurable
// this round (it was masked by the gemm regression).
// R13: byte-identical resubmit of R12 (round-12 bench was the third
// container-acquisition flake; rounds 5 and 9 resubmits both ran clean).

typedef __bf16 bf16x8 __attribute__((ext_vector_type(8)));
typedef float f32x4 __attribute__((ext_vector_type(4)));

#define BB 4
#define NQ 2048
#define NK 2048
#define DD 1024
#define HH 16
#define HD 64

#define QSCALE (0.125f * 1.4426950408889634f)  // 1/sqrt(HD) * log2(e)

#if __has_builtin(__builtin_amdgcn_exp2f)
#define EXP2F(x) __builtin_amdgcn_exp2f(x)
#else
#define EXP2F(x) exp2f(x)
#endif

__device__ inline void gld_lds16(const void* g, void* lds) {
  __builtin_amdgcn_global_load_lds(
      (__attribute__((address_space(1))) unsigned int*)(g),
      (__attribute__((address_space(3))) unsigned int*)(lds),
      16, 0, 0);
}

// fp32-vs-bf16 probe (FETCH_SIZE evidence: inputs are fp32; probe keeps the
// kernel correct either way).
__device__ inline bool probe_f32(const void* p) {
  const unsigned short* u = (const unsigned short*)p;
  int bad = 0;
#pragma unroll
  for (int i = 0; i < 64; ++i) {
    const int e = (u[2 * i] >> 7) & 0xFF;
    bad += (e > 0x8F) ? 1 : 0;
  }
  return bad >= 4;
}

__device__ inline bf16x8 cvt8(const float* src) {
  union { bf16x8 v; __hip_bfloat16 h[8]; } u;
#pragma unroll
  for (int j = 0; j < 8; ++j) u.h[j] = __float2bfloat16(src[j]);
  return u.v;
}

// ---------------------------------------------------------------------------
// cvt_all: fp32 -> bf16 (or bf16 copy) for q,k,v (512 blocks each) and the
// four W matrices (64 blocks each). 2048 vec8 per block, fully coalesced.
__global__ __launch_bounds__(256) void cvt_all(
    const void* __restrict__ q, const void* __restrict__ k,
    const void* __restrict__ v,
    const void* __restrict__ Wq, const void* __restrict__ Wk,
    const void* __restrict__ Wv, const void* __restrict__ Wo,
    __hip_bfloat16* __restrict__ qb, __hip_bfloat16* __restrict__ kb,
    __hip_bfloat16* __restrict__ vb, __hip_bfloat16* __restrict__ Wb) {
  const int bidx = blockIdx.x;
  const void* src; __hip_bfloat16* dst; size_t voff;
  if (bidx < 1536) {
    const int s = bidx >> 9;
    src = s == 0 ? q : (s == 1 ? k : v);
    dst = s == 0 ? qb : (s == 1 ? kb : vb);
    voff = (size_t)(bidx & 511) * 2048;
  } else {
    const int wi = (bidx - 1536) >> 6;
    src = wi == 0 ? Wq : (wi == 1 ? Wk : (wi == 2 ? Wv : Wo));
    dst = Wb + (size_t)wi * (DD * DD);
    voff = (size_t)((bidx - 1536) & 63) * 2048;
  }
  __shared__ int sflag;
  if (threadIdx.x == 0) sflag = probe_f32(src) ? 1 : 0;
  __syncthreads();
  const bool f32 = sflag != 0;
  const int t = threadIdx.x;
#pragma unroll
  for (int i = 0; i < 8; ++i) {
    const size_t j = voff + (size_t)i * 256 + t;
    if (f32) {
      union { f32x4 v2[2]; float f[8]; } u;
      const f32x4* s4 = (const f32x4*)src;
      u.v2[0] = s4[j * 2]; u.v2[1] = s4[j * 2 + 1];
      *(bf16x8*)(dst + j * 8) = cvt8(u.f);
    } else {
      *(f32x4*)(dst + j * 8) = ((const f32x4*)src)[j];
    }
  }
}

// ---------------------------------------------------------------------------
// gemm_fast: all-bf16 C[8192,1024] = A * W^T, epilogue (acc+bias)*scale.
// cfg = cfg0 + z: 0=Q(scale QSCALE) 1=K 2=V(Vt permute) 3=O(dtype-follow).
// m97-exact: BK=64, 128x128 tile, single-buffered 32KB LDS, 2 barriers/iter,
// 32 MFMA + 8 gld_lds16 + 16 ds_read_b128 per wave-iter. (256,3): the ,4
// bound spilled acc to scratch (R11: VGPR 64, 175MB writes) — keep 3.
// mode-1 epilogue: LDS-transpose (sT[col][row^swz] per wc-half in sA/sB),
// then coalesced 16B row writes into Vt.
// 1-D grid; decode: xcd=bid&7, idx=bid>>3, z=idx>>6, r=idx&63,
// bm=xcd*8+(r>>3), bn=r&7  (bn-fast within a bm stripe, per-XCD).
__global__ __launch_bounds__(256, 3) void gemm_fast(
    const __hip_bfloat16* __restrict__ qb, const __hip_bfloat16* __restrict__ kb,
    const __hip_bfloat16* __restrict__ vb, const __hip_bfloat16* __restrict__ At,
    const __hip_bfloat16* __restrict__ Wb,
    const void* __restrict__ bq, const void* __restrict__ bk,
    const void* __restrict__ bv, const void* __restrict__ bo,
    const void* __restrict__ WoOrig,
    void* __restrict__ Qp, void* __restrict__ Kp,
    void* __restrict__ Vt, void* __restrict__ Out, int cfg0) {
  __shared__ __align__(16) __hip_bfloat16 sA[128 * 64];
  __shared__ __align__(16) __hip_bfloat16 sB[128 * 64];
  const int t = threadIdx.x;
  const int wave = t >> 6, lane = t & 63;
  const int q4 = lane >> 4, c16 = lane & 15;
  const int xr = c16 & 7;
  const int wr = wave >> 1, wc = wave & 1;

  const int bid = blockIdx.x;
  const int xcd = bid & 7, idx = bid >> 3;
  const int z = idx >> 6;
  const int r6 = idx & 63;
  const int bm = xcd * 8 + (r6 >> 3);
  const int bn = r6 & 7;
  const int cfg = cfg0 + z;

  const __hip_bfloat16* A; const void* biasv; void* Cv; int mode; float scale = 1.f;
  if (cfg == 0)      { A = qb; biasv = bq; Cv = Qp; mode = 0; scale = QSCALE; }
  else if (cfg == 1) { A = kb; biasv = bk; Cv = Kp; mode = 0; }
  else if (cfg == 2) { A = vb; biasv = bv; Cv = Vt; mode = 1; }
  else               { A = At; biasv = bo; Cv = Out; mode = 2; }
  const __hip_bfloat16* Bm = Wb + (size_t)cfg * (DD * DD);

  const bool bias_f32 = probe_f32(biasv);
  const bool c_f32 = (mode == 2) && probe_f32(WoOrig);

  f32x4 acc[4][4];
#pragma unroll
  for (int i = 0; i < 4; ++i)
#pragma unroll
    for (int j = 0; j < 4; ++j) acc[i][j] = (f32x4){0.f, 0.f, 0.f, 0.f};

  const size_t baseA = (size_t)bm * 128 * DD;
  const size_t baseB = (size_t)bn * 128 * DD;

  // per-thread staging offsets (elements); slot=i*256+t (1024 slots of 16B),
  // row=slot>>3, pg=(slot&7)^(row&7) (source-side 8-piece swizzle)
  size_t offA[4], offB[4];
  int lslot[4];
#pragma unroll
  for (int i = 0; i < 4; ++i) {
    const int slot = i * 256 + t;
    const int row = slot >> 3, pg = (slot & 7) ^ (row & 7);
    lslot[i] = slot;
    offA[i] = baseA + (size_t)row * DD + pg * 8;
    offB[i] = baseB + (size_t)row * DD + pg * 8;
  }

  for (int k0 = 0; k0 < DD; k0 += 64) {
    __syncthreads();   // previous iteration's ds_reads complete
#pragma unroll
    for (int i = 0; i < 4; ++i)
      gld_lds16(A + offA[i] + k0, sA + lslot[i] * 8);
#pragma unroll
    for (int i = 0; i < 4; ++i)
      gld_lds16(Bm + offB[i] + k0, sB + lslot[i] * 8);
    __syncthreads();   // vmcnt(0) drain: tile staged

#pragma unroll
    for (int ks = 0; ks < 2; ++ks) {
      bf16x8 af[4], bfm[4];
#pragma unroll
      for (int rt = 0; rt < 4; ++rt)
        af[rt] = *(const bf16x8*)(sA + (wr * 64 + rt * 16 + c16) * 64 +
                                  ((ks * 4 + q4) ^ xr) * 8);
#pragma unroll
      for (int ct = 0; ct < 4; ++ct)
        bfm[ct] = *(const bf16x8*)(sB + (wc * 64 + ct * 16 + c16) * 64 +
                                   ((ks * 4 + q4) ^ xr) * 8);
#pragma unroll
      for (int rt = 0; rt < 4; ++rt)
#pragma unroll
        for (int ct = 0; ct < 4; ++ct)
          acc[rt][ct] = __builtin_amdgcn_mfma_f32_16x16x32_bf16(af[rt], bfm[ct],
                                                                acc[rt][ct], 0, 0, 0);
    }
  }

  if (mode == 1) {
    // Coalesced Vt epilogue: transpose via LDS. Wave-half wc -> sA (wc=0) /
    // sB (wc=1), layout sT[col(0..63)][row(0..127) ^ ((col&7)<<3)].
    __syncthreads();   // all MFMA reads of sA/sB done before overwrite
    __hip_bfloat16* sT = wc ? sB : sA;
#pragma unroll
    for (int ct = 0; ct < 4; ++ct) {
      const int col = ct * 16 + c16;                 // 0..63 within half
      const int colg = bn * 128 + wc * 64 + col;     // global n
      const float bvx = bias_f32 ? ((const float*)biasv)[colg]
                                 : __bfloat162float(((const __hip_bfloat16*)biasv)[colg]);
      const int sw = (col & 7) << 3;
#pragma unroll
      for (int rt = 0; rt < 4; ++rt) {
        union { uint2 u; __hip_bfloat16 hx[4]; } pk;
#pragma unroll
        for (int r = 0; r < 4; ++r)
          pk.hx[r] = __float2bfloat16((acc[rt][ct][r] + bvx) * scale);
        const int rowl = wr * 64 + rt * 16 + q4 * 4;
        *(uint2*)(sT + col * 128 + (rowl ^ sw)) = pk.u;
      }
    }
    __syncthreads();   // transpose staged (rows come from both wr waves)
    const int bb = bm >> 4;            // batch  (row>>11)
    const int kb0 = (bm & 15) * 128;   // key base (row&2047)
#pragma unroll
    for (int i = 0; i < 8; ++i) {
      const int idx2 = i * 256 + t;    // 0..2047 = 2 halves x 64 cols x 16 kc
      const int half = idx2 >> 10;
      const int rem = idx2 & 1023;
      const int col = rem >> 4;        // hd 0..63
      const int kc = rem & 15;         // 8-key chunk
      const __hip_bfloat16* sTh = half ? sB : sA;
      bf16x8 vv = *(const bf16x8*)(sTh + col * 128 + ((kc * 8) ^ ((col & 7) << 3)));
      const int hh = bn * 2 + half;
      *(bf16x8*)((__hip_bfloat16*)Cv +
                 (size_t)((bb * HH + hh) * HD + col) * NK + kb0 + kc * 8) = vv;
    }
    return;
  }

  // epilogue (modes 0,2): C/D layout row=(lane>>4)*4+reg, col=lane&15
  const int row0 = bm * 128 + wr * 64 + q4 * 4;
  const int col0 = bn * 128 + wc * 64 + c16;
#pragma unroll
  for (int ct = 0; ct < 4; ++ct) {
    const int col = col0 + ct * 16;
    const float bvx = bias_f32 ? ((const float*)biasv)[col]
                               : __bfloat162float(((const __hip_bfloat16*)biasv)[col]);
#pragma unroll
    for (int rt = 0; rt < 4; ++rt) {
#pragma unroll
      for (int r = 0; r < 4; ++r) {
        const int row = row0 + rt * 16 + r;
        const float val = (acc[rt][ct][r] + bvx) * scale;
        if (c_f32) {
          ((float*)Cv)[(size_t)row * DD + col] = val;
        } else {
          ((__hip_bfloat16*)Cv)[(size_t)row * DD + col] = __float2bfloat16(val);
        }
      }
    }
  }
}

// ---------------------------------------------------------------------------
// Fallback path (R3): reg-staged cvt gemm, used when ws is too small.
__device__ inline void ld_slot(bool f32, const void* basep, size_t eoff,
                               f32x4& lo, f32x4& hi) {
  if (f32) {
    const f32x4* p = (const f32x4*)((const float*)basep + eoff);
    lo = p[0]; hi = p[1];
  } else {
    lo = *(const f32x4*)((const __hip_bfloat16*)basep + eoff);
  }
}

__device__ inline void st_slot(bool f32, __hip_bfloat16* dst, f32x4 lo, f32x4 hi) {
  if (f32) {
    union { f32x4 v[2]; float f[8]; } u;
    u.v[0] = lo; u.v[1] = hi;
    *(bf16x8*)dst = cvt8(u.f);
  } else {
    *(f32x4*)dst = lo;
  }
}

__global__ __launch_bounds__(256, 3) void gemm_mha(
    const void* __restrict__ qin, const void* __restrict__ kin,
    const void* __restrict__ vin, const void* __restrict__ ain,
    const void* __restrict__ Wq, const void* __restrict__ bq,
    const void* __restrict__ Wk, const void* __restrict__ bk,
    const void* __restrict__ Wv, const void* __restrict__ bv,
    const void* __restrict__ Wo, const void* __restrict__ bo,
    void* __restrict__ Qp, void* __restrict__ Kp,
    void* __restrict__ Vt, void* __restrict__ Out, int cfg0) {
  __shared__ __align__(16) __hip_bfloat16 sA[2][128 * 32];
  __shared__ __align__(16) __hip_bfloat16 sB[2][128 * 32];
  const int t = threadIdx.x;
  const int wave = t >> 6, lane = t & 63;
  const int q4 = lane >> 4, c16 = lane & 15;
  const int wr = wave >> 1, wc = wave & 1;

  const int bid = blockIdx.x;
  const int xcd = bid & 7, idx = bid >> 3;
  const int z = idx >> 6;
  const int r6 = idx & 63;
  const int bm = xcd * 8 + (r6 >> 3);
  const int bn = r6 & 7;
  const int cfg = cfg0 + z;

  const void *Av, *Bv, *biasv; void* Cv; int mode; float scale = 1.f;
  if (cfg == 0)      { Av = qin; Bv = Wq; biasv = bq; Cv = Qp; mode = 0; scale = QSCALE; }
  else if (cfg == 1) { Av = kin; Bv = Wk; biasv = bk; Cv = Kp; mode = 0; }
  else if (cfg == 2) { Av = vin; Bv = Wv; biasv = bv; Cv = Vt; mode = 1; }
  else               { Av = ain; Bv = Wo; biasv = bo; Cv = Out; mode = 2; }

  const bool a_f32 = probe_f32(Av);
  const bool b_f32 = probe_f32(Bv);
  const bool c_f32 = (mode == 2) && b_f32;

  f32x4 acc[4][4];
#pragma unroll
  for (int i = 0; i < 4; ++i)
#pragma unroll
    for (int j = 0; j < 4; ++j) acc[i][j] = (f32x4){0.f, 0.f, 0.f, 0.f};

  const size_t baseA = (size_t)bm * 128 * DD;
  const size_t baseB = (size_t)bn * 128 * DD;
  const int po = ((q4) ^ (c16 & 3)) * 8;

  size_t offA[2], offB[2];
  int lslot[2];
#pragma unroll
  for (int i = 0; i < 2; ++i) {
    const int slot = i * 256 + t;
    const int row = slot >> 2, pg = (slot & 3) ^ (row & 3);
    lslot[i] = slot;
    offA[i] = baseA + (size_t)row * DD + pg * 8;
    offB[i] = baseB + (size_t)row * DD + pg * 8;
  }

  f32x4 Alo[2], Ahi[2], Blo[2], Bhi[2];
#pragma unroll
  for (int i = 0; i < 2; ++i) {
    ld_slot(a_f32, Av, offA[i], Alo[i], Ahi[i]);
    ld_slot(b_f32, Bv, offB[i], Blo[i], Bhi[i]);
  }

  for (int k0 = 0, it = 0; k0 < DD; k0 += 32, ++it) {
    const int p = it & 1;
#pragma unroll
    for (int i = 0; i < 2; ++i) {
      st_slot(a_f32, &sA[p][lslot[i] * 8], Alo[i], Ahi[i]);
      st_slot(b_f32, &sB[p][lslot[i] * 8], Blo[i], Bhi[i]);
    }
    __syncthreads();

    if (k0 + 32 < DD) {
#pragma unroll
      for (int i = 0; i < 2; ++i) {
        ld_slot(a_f32, Av, offA[i] + k0 + 32, Alo[i], Ahi[i]);
        ld_slot(b_f32, Bv, offB[i] + k0 + 32, Blo[i], Bhi[i]);
      }
    }

    bf16x8 af[4], bfm[4];
#pragma unroll
    for (int rt = 0; rt < 4; ++rt)
      af[rt] = *(const bf16x8*)(&sA[p][0] + (wr * 64 + rt * 16 + c16) * 32 + po);
#pragma unroll
    for (int ct = 0; ct < 4; ++ct)
      bfm[ct] = *(const bf16x8*)(&sB[p][0] + (wc * 64 + ct * 16 + c16) * 32 + po);
#pragma unroll
    for (int rt = 0; rt < 4; ++rt)
#pragma unroll
      for (int ct = 0; ct < 4; ++ct)
        acc[rt][ct] = __builtin_amdgcn_mfma_f32_16x16x32_bf16(af[rt], bfm[ct],
                                                              acc[rt][ct], 0, 0, 0);
  }

  const int row0 = bm * 128 + wr * 64 + q4 * 4;
  const int col0 = bn * 128 + wc * 64 + c16;
#pragma unroll
  for (int ct = 0; ct < 4; ++ct) {
    const int col = col0 + ct * 16;
    const float bvx = b_f32 ? ((const float*)biasv)[col]
                            : __bfloat162float(((const __hip_bfloat16*)biasv)[col]);
#pragma unroll
    for (int rt = 0; rt < 4; ++rt) {
#pragma unroll
      for (int r = 0; r < 4; ++r) {
        const int row = row0 + rt * 16 + r;
        const float val = (acc[rt][ct][r] + bvx) * scale;
        if (mode == 1) {
          const int b = row >> 11, key = row & 2047;
          const int h = col >> 6, hd = col & 63;
          ((__hip_bfloat16*)Cv)[(size_t)((b * HH + h) * HD + hd) * NK + key] =
              __float2bfloat16(val);
        } else if (c_f32) {
          ((float*)Cv)[(size_t)row * DD + col] = val;
        } else {
          ((__hip_bfloat16*)Cv)[(size_t)row * DD + col] = __float2bfloat16(val);
        }
      }
    }
  }
}

// ---------------------------------------------------------------------------
// Flash attention, S^T orientation. Qp pre-scaled by QSCALE (incl log2e);
// Kp: [B,N,D] bf16; Vt: [B,H,HD,NK]. One block = (b,h,128-query tile); wave
// owns 32 queries (2 groups of 16); K/bv LDS reads shared by both groups.
// V single-buffered; K double-buffered. LDS 40KB -> 4 blocks/CU.
// R11 (kept): l-sum via ones-MFMA: lacc[qg] = mfma(ap, ones, lacc) in the
// C-layout (lacc[r] <-> O-row q4*4+r on the same lane) -> removes 32 VALU
// adds/iter AND the end shfl reduce. s_setprio(1) wraps both MFMA clusters.
// 1-D grid (1024); decode: xcd=bid&7, idx=bid>>3, bh=xcd*8+(idx>>4),
// qt=idx&15.
__global__ __launch_bounds__(256, 4) void flash_attn(
    const __hip_bfloat16* Qp, const __hip_bfloat16* __restrict__ Kp,
    const __hip_bfloat16* __restrict__ Vt, __hip_bfloat16* Ao) {
  __shared__ __align__(16) __hip_bfloat16 sQP[128 * 64];  // Q[128][64] then P[128][64] (16 KB)
  __shared__ __align__(16) __hip_bfloat16 sK[2][64 * 64]; // 16 KB dbuf
  __shared__ __align__(16) __hip_bfloat16 sV[64 * 64];    // 8 KB single

  const int t = threadIdx.x;
  const int wave = t >> 6, lane = t & 63;
  const int q4 = lane >> 4, c16 = lane & 15;
  const int xr = c16 & 7;

  const int bid = blockIdx.x;
  const int xcd = bid & 7, idx = bid >> 3;   // idx 0..127
  const int bh = xcd * 8 + (idx >> 4);       // 0..63
  const int qt = idx & 15;                   // 0..15
  const int b = bh >> 4, h = bh & 15;

  // stage Q tile (128x64) + K tile 0, swizzled (pg=(slot&7)^(row&7))
#pragma unroll
  for (int i = 0; i < 4; ++i) {
    const int slot = i * 256 + t;
    const int row = slot >> 3, pg = (slot & 7) ^ (row & 7);
    gld_lds16(Qp + ((size_t)(b * NQ + qt * 128 + row) * DD + h * 64 + pg * 8),
              sQP + slot * 8);
  }
#pragma unroll
  for (int i = 0; i < 2; ++i) {
    const int slot = i * 256 + t;
    const int row = slot >> 3, pg = (slot & 7) ^ (row & 7);
    gld_lds16(Kp + ((size_t)(b * NK + row) * DD + h * 64 + pg * 8),
              &sK[0][0] + slot * 8);
  }

  f32x4 o[2][4];
#pragma unroll
  for (int g = 0; g < 2; ++g)
#pragma unroll
    for (int i = 0; i < 4; ++i) o[g][i] = (f32x4){0.f, 0.f, 0.f, 0.f};
  f32x4 lacc[2];
  lacc[0] = (f32x4){0.f, 0.f, 0.f, 0.f};
  lacc[1] = (f32x4){0.f, 0.f, 0.f, 0.f};

  // all-ones bf16x8 B-fragment for the l row-sum MFMA
  union { bf16x8 v; unsigned short u[8]; } one8;
#pragma unroll
  for (int j = 0; j < 8; ++j) one8.u[j] = 0x3F80;  // bf16 1.0

  __syncthreads();  // Q + K0 staged

  bf16x8 aq[2][2];
#pragma unroll
  for (int qg = 0; qg < 2; ++qg)
#pragma unroll
    for (int ks = 0; ks < 2; ++ks)
      aq[qg][ks] = *(const bf16x8*)(sQP + (wave * 32 + qg * 16 + c16) * 64 +
                                    ((ks * 4 + q4) ^ xr) * 8);
  // aq rows are wave-private (rows wave*32..+31) -> safe vs this wave's own
  // later P stores; cross-wave Q staging was fenced by the barrier above.

  const int prow0 = wave * 32 + c16;        // query group 0 row
  const int prow1 = wave * 32 + 16 + c16;   // query group 1 row

  for (int kt = 0; kt < NK / 64; ++kt) {
    const int p = kt & 1;
    // stage V[kt] into sV (prev iter's B2 guarantees PV[kt-1] reads done)
#pragma unroll
    for (int i = 0; i < 2; ++i) {
      const int slot = i * 256 + t;
      const int row = slot >> 3, pg = (slot & 7) ^ (row & 7);
      gld_lds16(Vt + ((size_t)(bh * 64 + row) * NK + kt * 64 + pg * 8),
                &sV[0] + slot * 8);
    }
    // prefetch K[kt+1] into sK[p^1]
    if (kt + 1 < NK / 64) {
#pragma unroll
      for (int i = 0; i < 2; ++i) {
        const int slot = i * 256 + t;
        const int row = slot >> 3, pg = (slot & 7) ^ (row & 7);
        gld_lds16(Kp + ((size_t)(b * NK + (kt + 1) * 64 + row) * DD + h * 64 + pg * 8),
                  &sK[p ^ 1][0] + slot * 8);
      }
    }

    // S^T tiles: keys ct*16+q4*4+r, query c16 per group (K reads shared)
    f32x4 s[2][4];
    __builtin_amdgcn_s_setprio(1);
#pragma unroll
    for (int ct = 0; ct < 4; ++ct) {
      bf16x8 bk0 = *(const bf16x8*)(&sK[p][0] + (ct * 16 + c16) * 64 + ((0 + q4) ^ xr) * 8);
      bf16x8 bk1 = *(const bf16x8*)(&sK[p][0] + (ct * 16 + c16) * 64 + ((4 + q4) ^ xr) * 8);
#pragma unroll
      for (int qg = 0; qg < 2; ++qg) {
        f32x4 z = (f32x4){0.f, 0.f, 0.f, 0.f};
        z = __builtin_amdgcn_mfma_f32_16x16x32_bf16(bk0, aq[qg][0], z, 0, 0, 0);
        z = __builtin_amdgcn_mfma_f32_16x16x32_bf16(bk1, aq[qg][1], z, 0, 0, 0);
        s[qg][ct] = z;
      }
    }
    __builtin_amdgcn_s_setprio(0);

    // p = exp2(s); pack 4 keys -> one 8B store into sP[query][key]
#pragma unroll
    for (int qg = 0; qg < 2; ++qg) {
      const int prow = qg ? prow1 : prow0;
#pragma unroll
      for (int ct = 0; ct < 4; ++ct) {
        union { uint2 u; __hip_bfloat16 hx[4]; } pk;
#pragma unroll
        for (int r = 0; r < 4; ++r)
          pk.hx[r] = __float2bfloat16(EXP2F(s[qg][ct][r]));
        const int pc = (ct * 2 + (q4 >> 1)) ^ xr;
        *(uint2*)(sQP + prow * 64 + pc * 8 + (q4 & 1) * 4) = pk.u;
      }
    }
    // P rows are wave-private: same-wave ds ordering suffices, no barrier.

    __syncthreads();  // B1: V[kt] (+K[kt+1]) drained into LDS

    // O += P V; l += P 1 (ones-MFMA; bv reads shared by both query groups)
    __builtin_amdgcn_s_setprio(1);
#pragma unroll
    for (int kk = 0; kk < 2; ++kk) {
      bf16x8 bvf[4];
#pragma unroll
      for (int ct2 = 0; ct2 < 4; ++ct2)
        bvf[ct2] = *(const bf16x8*)(&sV[0] + (ct2 * 16 + c16) * 64 + ((kk * 4 + q4) ^ xr) * 8);
      bf16x8 ap0 = *(const bf16x8*)(sQP + prow0 * 64 + ((kk * 4 + q4) ^ xr) * 8);
      bf16x8 ap1 = *(const bf16x8*)(sQP + prow1 * 64 + ((kk * 4 + q4) ^ xr) * 8);
      lacc[0] = __builtin_amdgcn_mfma_f32_16x16x32_bf16(ap0, one8.v, lacc[0], 0, 0, 0);
      lacc[1] = __builtin_amdgcn_mfma_f32_16x16x32_bf16(ap1, one8.v, lacc[1], 0, 0, 0);
#pragma unroll
      for (int ct2 = 0; ct2 < 4; ++ct2) {
        o[0][ct2] = __builtin_amdgcn_mfma_f32_16x16x32_bf16(ap0, bvf[ct2], o[0][ct2], 0, 0, 0);
        o[1][ct2] = __builtin_amdgcn_mfma_f32_16x16x32_bf16(ap1, bvf[ct2], o[1][ct2], 0, 0, 0);
      }
    }
    __builtin_amdgcn_s_setprio(0);

    __syncthreads();  // B2: PV reads done -> next iter may overwrite sV
  }

  // l is already per-lane complete: lacc[qg][r] = sum over all keys for
  // query row q4*4+r of group qg (replicated across c16) — the exact rows
  // this lane writes below. No cross-lane reduce needed.
  float linv[2][4];
#pragma unroll
  for (int qg = 0; qg < 2; ++qg)
#pragma unroll
    for (int r = 0; r < 4; ++r) linv[qg][r] = 1.f / lacc[qg][r];

  // epilogue: O C-layout row=query(q4*4+r), col=hd(ct2*16+c16)
#pragma unroll
  for (int qg = 0; qg < 2; ++qg)
#pragma unroll
    for (int ct2 = 0; ct2 < 4; ++ct2)
#pragma unroll
      for (int r = 0; r < 4; ++r) {
        const size_t row = (size_t)(b * NQ + qt * 128 + wave * 32 + qg * 16 + q4 * 4 + r);
        Ao[row * DD + h * 64 + ct2 * 16 + c16] = __float2bfloat16(o[qg][ct2][r] * linv[qg][r]);
      }
}

extern "C" void kernel_launch(void* const* d_in, const int* in_sizes, int n_in,
                              void* d_out, int out_size, void* d_ws, size_t ws_size,
                              hipStream_t stream) {
  const void* q  = d_in[0];
  const void* k  = d_in[1];
  const void* v  = d_in[2];
  const void* Wq = d_in[3];
  const void* bq = d_in[4];
  const void* Wk = d_in[5];
  const void* bk = d_in[6];
  const void* Wv = d_in[7];
  const void* bv = d_in[8];
  const void* Wo = d_in[9];
  const void* bo = d_in[10];

  const size_t MP = (size_t)BB * NQ;       // 8192
  const size_t MAT = MP * DD;              // 8.39M elems
  __hip_bfloat16* Qp = (__hip_bfloat16*)d_ws;   // also At (alias, safe)
  __hip_bfloat16* Vt = Qp + MAT;
  __hip_bfloat16* Kp = (__hip_bfloat16*)d_out;  // dead before final GEMM writes
  __hip_bfloat16* At = Qp;

  // fast path needs: Qp 16M | Vt 16M | kb 16M | vb 16M | Wb 8M = 72 MiB
  const size_t NEED = (4 * MAT + 4 * (size_t)(DD * DD)) * sizeof(__hip_bfloat16);
  if (ws_size >= NEED) {
    __hip_bfloat16* kb = Vt + MAT;
    __hip_bfloat16* vb = kb + MAT;
    __hip_bfloat16* Wb = vb + MAT;
    __hip_bfloat16* qb = (__hip_bfloat16*)d_out + MAT;  // upper half of d_out

    cvt_all<<<dim3(1792), 256, 0, stream>>>(q, k, v, Wq, Wk, Wv, Wo,
                                            qb, kb, vb, Wb);
    gemm_fast<<<dim3(1536), 256, 0, stream>>>(qb, kb, vb, At, Wb,
                                              bq, bk, bv, bo, Wo,
                                              Qp, Kp, Vt, d_out, 0);
    flash_attn<<<dim3(1024), 256, 0, stream>>>(Qp, Kp, Vt, At);
    gemm_fast<<<dim3(512), 256, 0, stream>>>(qb, kb, vb, At, Wb,
                                             bq, bk, bv, bo, Wo,
                                             Qp, Kp, Vt, d_out, 3);
  } else {
    // fallback: R3 path
    gemm_mha<<<dim3(1536), 256, 0, stream>>>(
        q, k, v, At, Wq, bq, Wk, bk, Wv, bv, Wo, bo, Qp, Kp, Vt, d_out, 0);
    flash_attn<<<dim3(1024), 256, 0, stream>>>(Qp, Kp, Vt, At);
    gemm_mha<<<dim3(512), 256, 0, stream>>>(
        q, k, v, At, Wq, bq, Wk, bk, Wv, bv, Wo, bo, Qp, Kp, Vt, d_out, 3);
  }
}

// Round 14
// 315.657 us; speedup vs baseline: 1.2480x; 1.0484x over previous
//
#include <hip/hip_runtime.h>
#include <hip/hip_bf16.h>
#include <cstdint>
#include <cstddef>

// MultiheadAttention: B=4, NQ=NK=2048, D=1024, H=16, HD=64.
// Pipeline (fast path, ws>=72MiB): cvt_all (fp32->bf16), gemm_fast QKV
// (NEW R14: 256x128 tile, 8 waves, triple-buffered LDS, counted-vmcnt
// pipeline), flash attention (R13: 32 q/wave, l-sum via ones-MFMA), O-proj.
// Score scale 1/8*log2(e) folded into Q-proj epilogue.
//
// R13 post-mortem: flash 91->82.6 (l-MFMA+setprio confirmed). flash pipes
// balanced (Mfma 40/VALU 41) near structure limit. GEMMs now ~108 us total
// at 640 TF = the m97-structure plateau (barrier vmcnt(0) drain each iter).
// R14: gemm_fast -> T3+T4 deep pipeline: BM=256 BN=128 BK=64, 512 thr
// (8 waves, wave tile 64x64 = same inner MFMA code), LDS 3 x 48KB = 144KB
// (1 block/CU), prefetch depth 2: iter t issues tile t+2 into buf (t+2)%3
// (last read at iter t-1, fenced by that iter's barrier); end-of-iter
// sync = asm vmcnt(6) [tile t+1 landed, t+2's 6 loads stay IN FLIGHT
// across the raw s_barrier] + sched_barrier(0) + "memory" fences (rule 18).
// Grid: QKV 768 = exactly 3 GPU-waves, O-proj 256 = 1 wave (no tails).

typedef __bf16 bf16x8 __attribute__((ext_vector_type(8)));
typedef float f32x4 __attribute__((ext_vector_type(4)));

#define BB 4
#define NQ 2048
#define NK 2048
#define DD 1024
#define HH 16
#define HD 64

#define QSCALE (0.125f * 1.4426950408889634f)  // 1/sqrt(HD) * log2(e)

#if __has_builtin(__builtin_amdgcn_exp2f)
#define EXP2F(x) __builtin_amdgcn_exp2f(x)
#else
#define EXP2F(x) exp2f(x)
#endif

__device__ inline void gld_lds16(const void* g, void* lds) {
  __builtin_amdgcn_global_load_lds(
      (__attribute__((address_space(1))) unsigned int*)(g),
      (__attribute__((address_space(3))) unsigned int*)(lds),
      16, 0, 0);
}

// fp32-vs-bf16 probe (FETCH_SIZE evidence: inputs are fp32; probe keeps the
// kernel correct either way).
__device__ inline bool probe_f32(const void* p) {
  const unsigned short* u = (const unsigned short*)p;
  int bad = 0;
#pragma unroll
  for (int i = 0; i < 64; ++i) {
    const int e = (u[2 * i] >> 7) & 0xFF;
    bad += (e > 0x8F) ? 1 : 0;
  }
  return bad >= 4;
}

__device__ inline bf16x8 cvt8(const float* src) {
  union { bf16x8 v; __hip_bfloat16 h[8]; } u;
#pragma unroll
  for (int j = 0; j < 8; ++j) u.h[j] = __float2bfloat16(src[j]);
  return u.v;
}

// ---------------------------------------------------------------------------
// cvt_all: fp32 -> bf16 (or bf16 copy) for q,k,v (512 blocks each) and the
// four W matrices (64 blocks each). 2048 vec8 per block, fully coalesced.
__global__ __launch_bounds__(256) void cvt_all(
    const void* __restrict__ q, const void* __restrict__ k,
    const void* __restrict__ v,
    const void* __restrict__ Wq, const void* __restrict__ Wk,
    const void* __restrict__ Wv, const void* __restrict__ Wo,
    __hip_bfloat16* __restrict__ qb, __hip_bfloat16* __restrict__ kb,
    __hip_bfloat16* __restrict__ vb, __hip_bfloat16* __restrict__ Wb) {
  const int bidx = blockIdx.x;
  const void* src; __hip_bfloat16* dst; size_t voff;
  if (bidx < 1536) {
    const int s = bidx >> 9;
    src = s == 0 ? q : (s == 1 ? k : v);
    dst = s == 0 ? qb : (s == 1 ? kb : vb);
    voff = (size_t)(bidx & 511) * 2048;
  } else {
    const int wi = (bidx - 1536) >> 6;
    src = wi == 0 ? Wq : (wi == 1 ? Wk : (wi == 2 ? Wv : Wo));
    dst = Wb + (size_t)wi * (DD * DD);
    voff = (size_t)((bidx - 1536) & 63) * 2048;
  }
  __shared__ int sflag;
  if (threadIdx.x == 0) sflag = probe_f32(src) ? 1 : 0;
  __syncthreads();
  const bool f32 = sflag != 0;
  const int t = threadIdx.x;
#pragma unroll
  for (int i = 0; i < 8; ++i) {
    const size_t j = voff + (size_t)i * 256 + t;
    if (f32) {
      union { f32x4 v2[2]; float f[8]; } u;
      const f32x4* s4 = (const f32x4*)src;
      u.v2[0] = s4[j * 2]; u.v2[1] = s4[j * 2 + 1];
      *(bf16x8*)(dst + j * 8) = cvt8(u.f);
    } else {
      *(f32x4*)(dst + j * 8) = ((const f32x4*)src)[j];
    }
  }
}

// ---------------------------------------------------------------------------
// gemm_fast (R14): all-bf16 C[8192,1024] = A * W^T, epilogue (acc+bias)*scale.
// cfg = cfg0 + z: 0=Q(scale QSCALE) 1=K 2=V(Vt permute) 3=O(dtype-follow).
// BM=256 BN=128 BK=64, 512 threads = 8 waves (4M x 2N, wave tile 64x64),
// triple-buffered LDS (3 x [A 256x64 + B 128x64] = 144 KB, 1 block/CU),
// counted-vmcnt pipeline: iter t issues tile t+2; end-of-iter waits
// vmcnt(6) (tile t+1 landed; t+2 stays in flight across raw s_barrier).
// Source-side 8-piece XOR swizzle (pg=(slot&7)^(row&7); reads XOR back).
// 1-D grid: QKV 768 (= 8 xcd x 3 z x 4 bm x 8 bn), O-proj 256.
// decode: xcd=bid&7, idx=bid>>3, z=idx>>5, r5=idx&31, bm=xcd*4+(r5>>3),
// bn=r5&7.
#define ABUF (256 * 64)
#define BBUF (128 * 64)
#define BUFSZ (ABUF + BBUF)

__global__ __launch_bounds__(512, 2) void gemm_fast(
    const __hip_bfloat16* __restrict__ qb, const __hip_bfloat16* __restrict__ kb,
    const __hip_bfloat16* __restrict__ vb, const __hip_bfloat16* __restrict__ At,
    const __hip_bfloat16* __restrict__ Wb,
    const void* __restrict__ bq, const void* __restrict__ bk,
    const void* __restrict__ bv, const void* __restrict__ bo,
    const void* __restrict__ WoOrig,
    void* __restrict__ Qp, void* __restrict__ Kp,
    void* __restrict__ Vt, void* __restrict__ Out, int cfg0) {
  __shared__ __align__(16) __hip_bfloat16 sm[3 * BUFSZ];  // 144 KB
  const int t = threadIdx.x;
  const int wave = t >> 6, lane = t & 63;
  const int q4 = lane >> 4, c16 = lane & 15;
  const int xr = c16 & 7;
  const int wr = wave >> 1, wc = wave & 1;   // 4M x 2N wave grid

  const int bid = blockIdx.x;
  const int xcd = bid & 7, idx = bid >> 3;
  const int z = idx >> 5;
  const int r5 = idx & 31;
  const int bm = xcd * 4 + (r5 >> 3);        // 0..31 (M tiles of 256)
  const int bn = r5 & 7;                     // 0..7  (N tiles of 128)
  const int cfg = cfg0 + z;

  const __hip_bfloat16* A; const void* biasv; void* Cv; int mode; float scale = 1.f;
  if (cfg == 0)      { A = qb; biasv = bq; Cv = Qp; mode = 0; scale = QSCALE; }
  else if (cfg == 1) { A = kb; biasv = bk; Cv = Kp; mode = 0; }
  else if (cfg == 2) { A = vb; biasv = bv; Cv = Vt; mode = 1; }
  else               { A = At; biasv = bo; Cv = Out; mode = 2; }
  const __hip_bfloat16* Bm = Wb + (size_t)cfg * (DD * DD);

  const bool bias_f32 = probe_f32(biasv);
  const bool c_f32 = (mode == 2) && probe_f32(WoOrig);

  f32x4 acc[4][4];
#pragma unroll
  for (int i = 0; i < 4; ++i)
#pragma unroll
    for (int j = 0; j < 4; ++j) acc[i][j] = (f32x4){0.f, 0.f, 0.f, 0.f};

  const size_t baseA = (size_t)bm * 256 * DD;
  const size_t baseB = (size_t)bn * 128 * DD;

  // staging: A 2048 slots (4/thread), B 1024 slots (2/thread); 16B each.
  size_t offA[4], offB[2];
  int slA[4], slB[2];
#pragma unroll
  for (int i = 0; i < 4; ++i) {
    const int slot = i * 512 + t;
    const int row = slot >> 3, pg = (slot & 7) ^ (row & 7);
    slA[i] = slot;
    offA[i] = baseA + (size_t)row * DD + pg * 8;
  }
#pragma unroll
  for (int i = 0; i < 2; ++i) {
    const int slot = i * 512 + t;
    const int row = slot >> 3, pg = (slot & 7) ^ (row & 7);
    slB[i] = slot;
    offB[i] = baseB + (size_t)row * DD + pg * 8;
  }

#define STAGE_TILE(bb, koff)                                          \
  {                                                                   \
    __hip_bfloat16* dA = sm + (bb) * BUFSZ;                           \
    __hip_bfloat16* dB = dA + ABUF;                                   \
    _Pragma("unroll")                                                 \
    for (int i = 0; i < 4; ++i)                                       \
      gld_lds16(A + offA[i] + (koff), dA + slA[i] * 8);               \
    _Pragma("unroll")                                                 \
    for (int i = 0; i < 2; ++i)                                       \
      gld_lds16(Bm + offB[i] + (koff), dB + slB[i] * 8);              \
  }

#define COMPUTE_TILE(bb)                                              \
  {                                                                   \
    const __hip_bfloat16* cA = sm + (bb) * BUFSZ;                     \
    const __hip_bfloat16* cB = cA + ABUF;                             \
    _Pragma("unroll")                                                 \
    for (int ks = 0; ks < 2; ++ks) {                                  \
      bf16x8 af[4], bfm[4];                                           \
      _Pragma("unroll")                                               \
      for (int rt = 0; rt < 4; ++rt)                                  \
        af[rt] = *(const bf16x8*)(cA + (wr * 64 + rt * 16 + c16) * 64 \
                                  + ((ks * 4 + q4) ^ xr) * 8);        \
      _Pragma("unroll")                                               \
      for (int ct = 0; ct < 4; ++ct)                                  \
        bfm[ct] = *(const bf16x8*)(cB + (wc * 64 + ct * 16 + c16) * 64\
                                   + ((ks * 4 + q4) ^ xr) * 8);       \
      _Pragma("unroll")                                               \
      for (int rt = 0; rt < 4; ++rt)                                  \
        _Pragma("unroll")                                             \
        for (int ct = 0; ct < 4; ++ct)                                \
          acc[rt][ct] = __builtin_amdgcn_mfma_f32_16x16x32_bf16(      \
              af[rt], bfm[ct], acc[rt][ct], 0, 0, 0);                 \
    }                                                                 \
  }

  // prologue: tiles 0,1 staged; wait tile0 only (tile1's 6 stay in flight)
  STAGE_TILE(0, 0);
  STAGE_TILE(1, 64);
  asm volatile("s_waitcnt vmcnt(6)" ::: "memory");
  __builtin_amdgcn_s_barrier();
  __builtin_amdgcn_sched_barrier(0);

#pragma unroll
  for (int tt = 0; tt < 16; ++tt) {
    // issue tile tt+2 into buf (tt+2)%3 — that buf's last readers ran at
    // iter tt-1 and were fenced by that iter's barrier.
    if (tt + 2 < 16) STAGE_TILE((tt + 2) % 3, (tt + 2) * 64);
    __builtin_amdgcn_s_setprio(1);
    COMPUTE_TILE(tt % 3);
    __builtin_amdgcn_s_setprio(0);
    if (tt + 1 < 16) {
      if (tt + 2 < 16) asm volatile("s_waitcnt vmcnt(6)" ::: "memory");
      else             asm volatile("s_waitcnt vmcnt(0)" ::: "memory");
      __builtin_amdgcn_s_barrier();
      __builtin_amdgcn_sched_barrier(0);
    }
  }

  if (mode == 1) {
    // Coalesced Vt epilogue: transpose 256x128 tile via LDS (first 64 KB of
    // sm). Layout sT[col 0..127][row 0..255 ^ ((col&7)<<3)].
    __syncthreads();   // all waves' tile-15 ds_reads done before overwrite
    __hip_bfloat16* sT = sm;
#pragma unroll
    for (int ct = 0; ct < 4; ++ct) {
      const int col = wc * 64 + ct * 16 + c16;       // 0..127
      const int colg = bn * 128 + col;               // global n
      const float bvx = bias_f32 ? ((const float*)biasv)[colg]
                                 : __bfloat162float(((const __hip_bfloat16*)biasv)[colg]);
      const int sw = (col & 7) << 3;
#pragma unroll
      for (int rt = 0; rt < 4; ++rt) {
        union { uint2 u; __hip_bfloat16 hx[4]; } pk;
#pragma unroll
        for (int r = 0; r < 4; ++r)
          pk.hx[r] = __float2bfloat16((acc[rt][ct][r] + bvx) * scale);
        const int rowl = wr * 64 + rt * 16 + q4 * 4; // 0..252
        *(uint2*)(sT + col * 256 + (rowl ^ sw)) = pk.u;
      }
    }
    __syncthreads();   // transpose staged
    const int bbat = bm >> 3;            // batch  (2048/256 = 8 bm per b)
    const int kb0 = (bm & 7) * 256;      // key base
#pragma unroll
    for (int i = 0; i < 8; ++i) {
      const int idx2 = i * 512 + t;      // 0..4095 = 128 cols x 32 kc
      const int col = idx2 >> 5;         // hd-half 0..127
      const int kc = idx2 & 31;          // 8-key chunk
      bf16x8 vv = *(const bf16x8*)(sT + col * 256 + ((kc * 8) ^ ((col & 7) << 3)));
      const int hh = bn * 2 + (col >> 6);
      const int hd = col & 63;
      *(bf16x8*)((__hip_bfloat16*)Cv +
                 (size_t)((bbat * HH + hh) * HD + hd) * NK + kb0 + kc * 8) = vv;
    }
    return;
  }

  // epilogue (modes 0,2): C/D layout row=(lane>>4)*4+reg, col=lane&15
  const int row0 = bm * 256 + wr * 64 + q4 * 4;
  const int col0 = bn * 128 + wc * 64 + c16;
#pragma unroll
  for (int ct = 0; ct < 4; ++ct) {
    const int col = col0 + ct * 16;
    const float bvx = bias_f32 ? ((const float*)biasv)[col]
                               : __bfloat162float(((const __hip_bfloat16*)biasv)[col]);
#pragma unroll
    for (int rt = 0; rt < 4; ++rt) {
#pragma unroll
      for (int r = 0; r < 4; ++r) {
        const int row = row0 + rt * 16 + r;
        const float val = (acc[rt][ct][r] + bvx) * scale;
        if (c_f32) {
          ((float*)Cv)[(size_t)row * DD + col] = val;
        } else {
          ((__hip_bfloat16*)Cv)[(size_t)row * DD + col] = __float2bfloat16(val);
        }
      }
    }
  }
}
#undef STAGE_TILE
#undef COMPUTE_TILE

// ---------------------------------------------------------------------------
// Fallback path (R3): reg-staged cvt gemm, used when ws is too small.
__device__ inline void ld_slot(bool f32, const void* basep, size_t eoff,
                               f32x4& lo, f32x4& hi) {
  if (f32) {
    const f32x4* p = (const f32x4*)((const float*)basep + eoff);
    lo = p[0]; hi = p[1];
  } else {
    lo = *(const f32x4*)((const __hip_bfloat16*)basep + eoff);
  }
}

__device__ inline void st_slot(bool f32, __hip_bfloat16* dst, f32x4 lo, f32x4 hi) {
  if (f32) {
    union { f32x4 v[2]; float f[8]; } u;
    u.v[0] = lo; u.v[1] = hi;
    *(bf16x8*)dst = cvt8(u.f);
  } else {
    *(f32x4*)dst = lo;
  }
}

__global__ __launch_bounds__(256, 3) void gemm_mha(
    const void* __restrict__ qin, const void* __restrict__ kin,
    const void* __restrict__ vin, const void* __restrict__ ain,
    const void* __restrict__ Wq, const void* __restrict__ bq,
    const void* __restrict__ Wk, const void* __restrict__ bk,
    const void* __restrict__ Wv, const void* __restrict__ bv,
    const void* __restrict__ Wo, const void* __restrict__ bo,
    void* __restrict__ Qp, void* __restrict__ Kp,
    void* __restrict__ Vt, void* __restrict__ Out, int cfg0) {
  __shared__ __align__(16) __hip_bfloat16 sA[2][128 * 32];
  __shared__ __align__(16) __hip_bfloat16 sB[2][128 * 32];
  const int t = threadIdx.x;
  const int wave = t >> 6, lane = t & 63;
  const int q4 = lane >> 4, c16 = lane & 15;
  const int wr = wave >> 1, wc = wave & 1;

  const int bid = blockIdx.x;
  const int xcd = bid & 7, idx = bid >> 3;
  const int z = idx >> 6;
  const int r6 = idx & 63;
  const int bm = xcd * 8 + (r6 >> 3);
  const int bn = r6 & 7;
  const int cfg = cfg0 + z;

  const void *Av, *Bv, *biasv; void* Cv; int mode; float scale = 1.f;
  if (cfg == 0)      { Av = qin; Bv = Wq; biasv = bq; Cv = Qp; mode = 0; scale = QSCALE; }
  else if (cfg == 1) { Av = kin; Bv = Wk; biasv = bk; Cv = Kp; mode = 0; }
  else if (cfg == 2) { Av = vin; Bv = Wv; biasv = bv; Cv = Vt; mode = 1; }
  else               { Av = ain; Bv = Wo; biasv = bo; Cv = Out; mode = 2; }

  const bool a_f32 = probe_f32(Av);
  const bool b_f32 = probe_f32(Bv);
  const bool c_f32 = (mode == 2) && b_f32;

  f32x4 acc[4][4];
#pragma unroll
  for (int i = 0; i < 4; ++i)
#pragma unroll
    for (int j = 0; j < 4; ++j) acc[i][j] = (f32x4){0.f, 0.f, 0.f, 0.f};

  const size_t baseA = (size_t)bm * 128 * DD;
  const size_t baseB = (size_t)bn * 128 * DD;
  const int po = ((q4) ^ (c16 & 3)) * 8;

  size_t offA[2], offB[2];
  int lslot[2];
#pragma unroll
  for (int i = 0; i < 2; ++i) {
    const int slot = i * 256 + t;
    const int row = slot >> 2, pg = (slot & 3) ^ (row & 3);
    lslot[i] = slot;
    offA[i] = baseA + (size_t)row * DD + pg * 8;
    offB[i] = baseB + (size_t)row * DD + pg * 8;
  }

  f32x4 Alo[2], Ahi[2], Blo[2], Bhi[2];
#pragma unroll
  for (int i = 0; i < 2; ++i) {
    ld_slot(a_f32, Av, offA[i], Alo[i], Ahi[i]);
    ld_slot(b_f32, Bv, offB[i], Blo[i], Bhi[i]);
  }

  for (int k0 = 0, it = 0; k0 < DD; k0 += 32, ++it) {
    const int p = it & 1;
#pragma unroll
    for (int i = 0; i < 2; ++i) {
      st_slot(a_f32, &sA[p][lslot[i] * 8], Alo[i], Ahi[i]);
      st_slot(b_f32, &sB[p][lslot[i] * 8], Blo[i], Bhi[i]);
    }
    __syncthreads();

    if (k0 + 32 < DD) {
#pragma unroll
      for (int i = 0; i < 2; ++i) {
        ld_slot(a_f32, Av, offA[i] + k0 + 32, Alo[i], Ahi[i]);
        ld_slot(b_f32, Bv, offB[i] + k0 + 32, Blo[i], Bhi[i]);
      }
    }

    bf16x8 af[4], bfm[4];
#pragma unroll
    for (int rt = 0; rt < 4; ++rt)
      af[rt] = *(const bf16x8*)(&sA[p][0] + (wr * 64 + rt * 16 + c16) * 32 + po);
#pragma unroll
    for (int ct = 0; ct < 4; ++ct)
      bfm[ct] = *(const bf16x8*)(&sB[p][0] + (wc * 64 + ct * 16 + c16) * 32 + po);
#pragma unroll
    for (int rt = 0; rt < 4; ++rt)
#pragma unroll
      for (int ct = 0; ct < 4; ++ct)
        acc[rt][ct] = __builtin_amdgcn_mfma_f32_16x16x32_bf16(af[rt], bfm[ct],
                                                              acc[rt][ct], 0, 0, 0);
  }

  const int row0 = bm * 128 + wr * 64 + q4 * 4;
  const int col0 = bn * 128 + wc * 64 + c16;
#pragma unroll
  for (int ct = 0; ct < 4; ++ct) {
    const int col = col0 + ct * 16;
    const float bvx = b_f32 ? ((const float*)biasv)[col]
                            : __bfloat162float(((const __hip_bfloat16*)biasv)[col]);
#pragma unroll
    for (int rt = 0; rt < 4; ++rt) {
#pragma unroll
      for (int r = 0; r < 4; ++r) {
        const int row = row0 + rt * 16 + r;
        const float val = (acc[rt][ct][r] + bvx) * scale;
        if (mode == 1) {
          const int b = row >> 11, key = row & 2047;
          const int h = col >> 6, hd = col & 63;
          ((__hip_bfloat16*)Cv)[(size_t)((b * HH + h) * HD + hd) * NK + key] =
              __float2bfloat16(val);
        } else if (c_f32) {
          ((float*)Cv)[(size_t)row * DD + col] = val;
        } else {
          ((__hip_bfloat16*)Cv)[(size_t)row * DD + col] = __float2bfloat16(val);
        }
      }
    }
  }
}

// ---------------------------------------------------------------------------
// Flash attention (unchanged from R13, measured 82.6 us). S^T orientation.
// Qp pre-scaled by QSCALE (incl log2e); Kp: [B,N,D] bf16; Vt: [B,H,HD,NK].
// One block = (b,h,128-query tile); wave owns 32 queries (2 groups of 16).
// V single-buffered; K double-buffered; LDS 40KB -> 4 blocks/CU.
// l-sum via ones-MFMA in C-layout; setprio around MFMA clusters.
__global__ __launch_bounds__(256, 4) void flash_attn(
    const __hip_bfloat16* Qp, const __hip_bfloat16* __restrict__ Kp,
    const __hip_bfloat16* __restrict__ Vt, __hip_bfloat16* Ao) {
  __shared__ __align__(16) __hip_bfloat16 sQP[128 * 64];  // Q then P (16 KB)
  __shared__ __align__(16) __hip_bfloat16 sK[2][64 * 64]; // 16 KB dbuf
  __shared__ __align__(16) __hip_bfloat16 sV[64 * 64];    // 8 KB single

  const int t = threadIdx.x;
  const int wave = t >> 6, lane = t & 63;
  const int q4 = lane >> 4, c16 = lane & 15;
  const int xr = c16 & 7;

  const int bid = blockIdx.x;
  const int xcd = bid & 7, idx = bid >> 3;   // idx 0..127
  const int bh = xcd * 8 + (idx >> 4);       // 0..63
  const int qt = idx & 15;                   // 0..15
  const int b = bh >> 4, h = bh & 15;

#pragma unroll
  for (int i = 0; i < 4; ++i) {
    const int slot = i * 256 + t;
    const int row = slot >> 3, pg = (slot & 7) ^ (row & 7);
    gld_lds16(Qp + ((size_t)(b * NQ + qt * 128 + row) * DD + h * 64 + pg * 8),
              sQP + slot * 8);
  }
#pragma unroll
  for (int i = 0; i < 2; ++i) {
    const int slot = i * 256 + t;
    const int row = slot >> 3, pg = (slot & 7) ^ (row & 7);
    gld_lds16(Kp + ((size_t)(b * NK + row) * DD + h * 64 + pg * 8),
              &sK[0][0] + slot * 8);
  }

  f32x4 o[2][4];
#pragma unroll
  for (int g = 0; g < 2; ++g)
#pragma unroll
    for (int i = 0; i < 4; ++i) o[g][i] = (f32x4){0.f, 0.f, 0.f, 0.f};
  f32x4 lacc[2];
  lacc[0] = (f32x4){0.f, 0.f, 0.f, 0.f};
  lacc[1] = (f32x4){0.f, 0.f, 0.f, 0.f};

  union { bf16x8 v; unsigned short u[8]; } one8;
#pragma unroll
  for (int j = 0; j < 8; ++j) one8.u[j] = 0x3F80;  // bf16 1.0

  __syncthreads();  // Q + K0 staged

  bf16x8 aq[2][2];
#pragma unroll
  for (int qg = 0; qg < 2; ++qg)
#pragma unroll
    for (int ks = 0; ks < 2; ++ks)
      aq[qg][ks] = *(const bf16x8*)(sQP + (wave * 32 + qg * 16 + c16) * 64 +
                                    ((ks * 4 + q4) ^ xr) * 8);

  const int prow0 = wave * 32 + c16;
  const int prow1 = wave * 32 + 16 + c16;

  for (int kt = 0; kt < NK / 64; ++kt) {
    const int p = kt & 1;
#pragma unroll
    for (int i = 0; i < 2; ++i) {
      const int slot = i * 256 + t;
      const int row = slot >> 3, pg = (slot & 7) ^ (row & 7);
      gld_lds16(Vt + ((size_t)(bh * 64 + row) * NK + kt * 64 + pg * 8),
                &sV[0] + slot * 8);
    }
    if (kt + 1 < NK / 64) {
#pragma unroll
      for (int i = 0; i < 2; ++i) {
        const int slot = i * 256 + t;
        const int row = slot >> 3, pg = (slot & 7) ^ (row & 7);
        gld_lds16(Kp + ((size_t)(b * NK + (kt + 1) * 64 + row) * DD + h * 64 + pg * 8),
                  &sK[p ^ 1][0] + slot * 8);
      }
    }

    f32x4 s[2][4];
    __builtin_amdgcn_s_setprio(1);
#pragma unroll
    for (int ct = 0; ct < 4; ++ct) {
      bf16x8 bk0 = *(const bf16x8*)(&sK[p][0] + (ct * 16 + c16) * 64 + ((0 + q4) ^ xr) * 8);
      bf16x8 bk1 = *(const bf16x8*)(&sK[p][0] + (ct * 16 + c16) * 64 + ((4 + q4) ^ xr) * 8);
#pragma unroll
      for (int qg = 0; qg < 2; ++qg) {
        f32x4 z = (f32x4){0.f, 0.f, 0.f, 0.f};
        z = __builtin_amdgcn_mfma_f32_16x16x32_bf16(bk0, aq[qg][0], z, 0, 0, 0);
        z = __builtin_amdgcn_mfma_f32_16x16x32_bf16(bk1, aq[qg][1], z, 0, 0, 0);
        s[qg][ct] = z;
      }
    }
    __builtin_amdgcn_s_setprio(0);

#pragma unroll
    for (int qg = 0; qg < 2; ++qg) {
      const int prow = qg ? prow1 : prow0;
#pragma unroll
      for (int ct = 0; ct < 4; ++ct) {
        union { uint2 u; __hip_bfloat16 hx[4]; } pk;
#pragma unroll
        for (int r = 0; r < 4; ++r)
          pk.hx[r] = __float2bfloat16(EXP2F(s[qg][ct][r]));
        const int pc = (ct * 2 + (q4 >> 1)) ^ xr;
        *(uint2*)(sQP + prow * 64 + pc * 8 + (q4 & 1) * 4) = pk.u;
      }
    }

    __syncthreads();  // B1: V[kt] (+K[kt+1]) drained into LDS

    __builtin_amdgcn_s_setprio(1);
#pragma unroll
    for (int kk = 0; kk < 2; ++kk) {
      bf16x8 bvf[4];
#pragma unroll
      for (int ct2 = 0; ct2 < 4; ++ct2)
        bvf[ct2] = *(const bf16x8*)(&sV[0] + (ct2 * 16 + c16) * 64 + ((kk * 4 + q4) ^ xr) * 8);
      bf16x8 ap0 = *(const bf16x8*)(sQP + prow0 * 64 + ((kk * 4 + q4) ^ xr) * 8);
      bf16x8 ap1 = *(const bf16x8*)(sQP + prow1 * 64 + ((kk * 4 + q4) ^ xr) * 8);
      lacc[0] = __builtin_amdgcn_mfma_f32_16x16x32_bf16(ap0, one8.v, lacc[0], 0, 0, 0);
      lacc[1] = __builtin_amdgcn_mfma_f32_16x16x32_bf16(ap1, one8.v, lacc[1], 0, 0, 0);
#pragma unroll
      for (int ct2 = 0; ct2 < 4; ++ct2) {
        o[0][ct2] = __builtin_amdgcn_mfma_f32_16x16x32_bf16(ap0, bvf[ct2], o[0][ct2], 0, 0, 0);
        o[1][ct2] = __builtin_amdgcn_mfma_f32_16x16x32_bf16(ap1, bvf[ct2], o[1][ct2], 0, 0, 0);
      }
    }
    __builtin_amdgcn_s_setprio(0);

    __syncthreads();  // B2: PV reads done -> next iter may overwrite sV
  }

  float linv[2][4];
#pragma unroll
  for (int qg = 0; qg < 2; ++qg)
#pragma unroll
    for (int r = 0; r < 4; ++r) linv[qg][r] = 1.f / lacc[qg][r];

#pragma unroll
  for (int qg = 0; qg < 2; ++qg)
#pragma unroll
    for (int ct2 = 0; ct2 < 4; ++ct2)
#pragma unroll
      for (int r = 0; r < 4; ++r) {
        const size_t row = (size_t)(b * NQ + qt * 128 + wave * 32 + qg * 16 + q4 * 4 + r);
        Ao[row * DD + h * 64 + ct2 * 16 + c16] = __float2bfloat16(o[qg][ct2][r] * linv[qg][r]);
      }
}

extern "C" void kernel_launch(void* const* d_in, const int* in_sizes, int n_in,
                              void* d_out, int out_size, void* d_ws, size_t ws_size,
                              hipStream_t stream) {
  const void* q  = d_in[0];
  const void* k  = d_in[1];
  const void* v  = d_in[2];
  const void* Wq = d_in[3];
  const void* bq = d_in[4];
  const void* Wk = d_in[5];
  const void* bk = d_in[6];
  const void* Wv = d_in[7];
  const void* bv = d_in[8];
  const void* Wo = d_in[9];
  const void* bo = d_in[10];

  const size_t MP = (size_t)BB * NQ;       // 8192
  const size_t MAT = MP * DD;              // 8.39M elems
  __hip_bfloat16* Qp = (__hip_bfloat16*)d_ws;   // also At (alias, safe)
  __hip_bfloat16* Vt = Qp + MAT;
  __hip_bfloat16* Kp = (__hip_bfloat16*)d_out;  // dead before final GEMM writes
  __hip_bfloat16* At = Qp;

  // fast path needs: Qp 16M | Vt 16M | kb 16M | vb 16M | Wb 8M = 72 MiB
  const size_t NEED = (4 * MAT + 4 * (size_t)(DD * DD)) * sizeof(__hip_bfloat16);
  if (ws_size >= NEED) {
    __hip_bfloat16* kb = Vt + MAT;
    __hip_bfloat16* vb = kb + MAT;
    __hip_bfloat16* Wb = vb + MAT;
    __hip_bfloat16* qb = (__hip_bfloat16*)d_out + MAT;  // upper half of d_out

    cvt_all<<<dim3(1792), 256, 0, stream>>>(q, k, v, Wq, Wk, Wv, Wo,
                                            qb, kb, vb, Wb);
    gemm_fast<<<dim3(768), 512, 0, stream>>>(qb, kb, vb, At, Wb,
                                             bq, bk, bv, bo, Wo,
                                             Qp, Kp, Vt, d_out, 0);
    flash_attn<<<dim3(1024), 256, 0, stream>>>(Qp, Kp, Vt, At);
    gemm_fast<<<dim3(256), 512, 0, stream>>>(qb, kb, vb, At, Wb,
                                             bq, bk, bv, bo, Wo,
                                             Qp, Kp, Vt, d_out, 3);
  } else {
    // fallback: R3 path
    gemm_mha<<<dim3(1536), 256, 0, stream>>>(
        q, k, v, At, Wq, bq, Wk, bk, Wv, bv, Wo, bo, Qp, Kp, Vt, d_out, 0);
    flash_attn<<<dim3(1024), 256, 0, stream>>>(Qp, Kp, Vt, At);
    gemm_mha<<<dim3(512), 256, 0, stream>>>(
        q, k, v, At, Wq, bq, Wk, bk, Wv, bv, Wo, bo, Qp, Kp, Vt, d_out, 3);
  }
}